// Round 1
// baseline (183.616 us; speedup 1.0000x reference)
//
#include <hip/hip_runtime.h>

// R18: fuse the 3 GNN launches into ONE persistent kernel with XCD-local
// per-(b,row) ready-flags. The R13 per-layer pipeline body is UNCHANGED.
// Rationale: MfmaUtil ~4% / VALUBusy ~13% / HBM ~30% = serialization plateau;
// VALU-issue arithmetic (~12us) matches VALUBusy over the 112us window, so
// ~75% of wall time is stall concentrated at dispatch boundaries (L1+L2
// acquire-invalidate per dispatch -> each layer re-reads 16-32MB cold).
// Row dependencies are row+-1 within one batch element; the XCD-aligned remap
// puts all 64 rows of a batch on ONE XCD, so inter-layer sync needs only
// same-XCD L2 visibility: producer __syncthreads (vmcnt(0) drain -> stores in
// XCD L2, L1 is write-through) + relaxed agent flag store; consumer relaxed
// agent flag poll. NO fences / cache maintenance (avoids R10's coherence
// storm). Residency: __launch_bounds__(256,4) + grid 1024 = 4/CU exact;
// bounded spin fails loud (absmax) instead of hanging if that ever breaks.
//
// Intermediates FEATURE-MAJOR h[b][f][n], n = 64x64 grid.
// GNN layer exact rewrite: h' = relu( agg(h) @ W + rowsum*b ).
// fp32 split a = hi + lo (bf16); 3 MFMAs: hi*wh + hi*wl + lo*wh.
//
// MFMA 16x16x32 bf16 layouts (verified m89/m120):
//   A (MxK): m = lane&15, k = quad*8 + j    B (KxN): n = lane&15, k = quad*8 + j
//   C/D: col(N) = lane&15, row(M) = quad*4 + reg

typedef __attribute__((ext_vector_type(8))) short bf16x8;
typedef __attribute__((ext_vector_type(4))) float f32x4;
#define MFMA(a, b, c) __builtin_amdgcn_mfma_f32_16x16x32_bf16(a, b, c, 0, 0, 0)

// barrier with LDS visibility but WITHOUT draining global loads:
// s_waitcnt imm 0xC07F = vmcnt(63) expcnt(7) lgkmcnt(0)
__device__ inline void block_sync_lgkm() {
    asm volatile("" ::: "memory");
    __builtin_amdgcn_s_waitcnt(0xC07F);
    __builtin_amdgcn_s_barrier();
    asm volatile("" ::: "memory");
}

__device__ inline ushort bf16h(float x) {
    unsigned u = __float_as_uint(x);
    return (ushort)((u + 0x7fffu + ((u >> 16) & 1u)) >> 16);
}
__device__ inline void split_bf16(float x, ushort& hi, ushort& lo) {
    hi = bf16h(x);
    lo = bf16h(x - __uint_as_float(((unsigned)hi) << 16));
}
// packed (hi16 << 16) | lo16 ; hi = RNE, lo = truncation
__device__ inline unsigned pack_split(float x) {
    unsigned u = __float_as_uint(x);
    unsigned hi = (u + 0x7fffu + ((u >> 16) & 1u)) >> 16;
    float r = x - __uint_as_float(hi << 16);
    return (hi << 16) | (__float_as_uint(r) >> 16);
}
// 8 packed u32 (stride 65) -> hi/lo bf16x8 fragments
__device__ inline void frag_packed(const unsigned* bp, bf16x8& bh, bf16x8& bl) {
    unsigned p[8];
#pragma unroll
    for (int j = 0; j < 8; j++) p[j] = bp[j * 65];
    union { bf16x8 v; unsigned d[4]; } H, L;
#pragma unroll
    for (int j = 0; j < 4; j++) {
        const unsigned e = p[2 * j], o = p[2 * j + 1];
        H.d[j] = (o & 0xFFFF0000u) | (e >> 16);
        L.d[j] = (o << 16) | (e & 0xFFFFu);
    }
    bh = H.v; bl = L.v;
}

// ---- fused launch 1: g-weight prep (blk<20) + gsum zero (blk<28) +
//      flag zero (blk<36) + embed ----
// g-frag unit (kc,t) = 2 planes x 512 ushorts; per layer unit idx = kc*8 + t.
// wfb ushort offsets: g1@12288 (16 units), g2@28672 (32), g3@61440 (32).
__global__ __launch_bounds__(256, 4) void prep_embed_kernel(
    const float* __restrict__ obs,
    const float* __restrict__ e1w, const float* __restrict__ e1b,
    const float* __restrict__ e2w, const float* __restrict__ e2b,
    const float* __restrict__ g1w, const float* __restrict__ g2w,
    const float* __restrict__ g3w, ushort* __restrict__ wf,
    float* __restrict__ gsum, float* __restrict__ h0,
    unsigned* __restrict__ flags)
{
    const int blk = blockIdx.x, tid = threadIdx.x;

    if (blk < 20) {                        // ---- g-weight prep: 4 units/block ----
        const int u = blk * 4 + (tid >> 6);
        const int l = tid & 63;
        const float* src; int K, kc, t; ushort* dst;
        if (u < 16)      { src = g1w; K = 64;  kc = u >> 3;        t = u & 7; dst = wf + 12288; }
        else if (u < 48) { src = g2w; K = 128; kc = (u - 16) >> 3; t = (u - 16) & 7; dst = wf + 28672; }
        else             { src = g3w; K = 128; kc = (u - 48) >> 3; t = (u - 48) & 7; dst = wf + 61440; }
        ushort* uh = dst + ((kc * 8 + t) * 2 + 0) * 512 + l * 8;
        ushort* ul = dst + ((kc * 8 + t) * 2 + 1) * 512 + l * 8;
        const int f = t * 16 + (l & 15);
        const int kb = kc * 32 + ((l >> 4) << 3);
#pragma unroll
        for (int j = 0; j < 8; j++) {
            const int k = kb + j;
            const float w = (k < K) ? src[k * 128 + f] : 0.f;
            ushort hi, lo; split_bf16(w, hi, lo);
            uh[j] = hi; ul[j] = lo;
        }
        return;
    }
    if (blk < 28) {                        // ---- zero gsum (8 x 256 = 2048) ----
        gsum[(blk - 20) * 256 + tid] = 0.f;
        return;
    }
    if (blk < 36) {                        // ---- zero ready-flags (2 x 1024) ----
        flags[(blk - 28) * 256 + tid] = 0u;
        return;
    }

    // ---- embed: block = (b, row) = 64 nodes, fused 2-layer MLP via MFMA ----
    __shared__ unsigned lds[6240];         // phase W: raw e1w|e2w (5120 f32)
                                           // then Xs = lds[0..2080), Hs = lds+2080
    // XCD remap ALIGNED with gnn readers: h0 rows land on the XCD that reads them
    const int eb = blk - 36;
    const int ebid = ((eb & 7) << 7) | (eb >> 3);
    const int b = ebid >> 6, row = ebid & 63;
    const int lane = tid & 63, w = tid >> 6, quad = lane >> 4, nl = lane & 15;
    const int cp = tid >> 4, nq = tid & 15;

    // obs load issued early (used in phase X)
    const float4 x4 = *(const float4*)(obs + ((size_t)(b * 16 + cp) << 12) + row * 64 + nq * 4);

    // phase W: stage raw e1w (1024 f) + e2w (4096 f) into LDS, coalesced
    {
        float* wr = (float*)lds;
#pragma unroll
        for (int i = 0; i < 20; i++) {
            const int idx = tid + 256 * i;
            wr[idx] = (idx < 1024) ? e1w[idx] : e2w[idx - 1024];
        }
    }
    __syncthreads();

    // build this wave's weight fragments in registers (A-operand, M=feats)
    bf16x8 e1h, e1l, e2h[2], e2l[2];
    {
        const float* wr = (const float*)lds;
        const int f = 16 * w + nl;
#pragma unroll
        for (int j = 0; j < 8; j++) {
            const int k = quad * 8 + j;
            const float v = (k < 16) ? wr[k * 64 + f] : 0.f;
            ushort hi, lo; split_bf16(v, hi, lo);
            e1h[j] = (short)hi; e1l[j] = (short)lo;
        }
#pragma unroll
        for (int kc = 0; kc < 2; kc++)
#pragma unroll
            for (int j = 0; j < 8; j++) {
                const int k = kc * 32 + quad * 8 + j;
                const float v = wr[1024 + k * 64 + f];
                ushort hi, lo; split_bf16(v, hi, lo);
                e2h[kc][j] = (short)hi; e2l[kc][j] = (short)lo;
            }
    }
    __syncthreads();

    // phase X: stage obs packed (B-operand planes, k>=16 zeroed)
    unsigned* Xs = lds;
    unsigned* Hs = lds + 2080;
    {
        unsigned* xp = Xs + cp * 65 + nq * 4;
        xp[0] = pack_split(x4.x); xp[1] = pack_split(x4.y);
        xp[2] = pack_split(x4.z); xp[3] = pack_split(x4.w);
        unsigned* zp = Xs + (16 + cp) * 65 + nq * 4;
        zp[0] = 0u; zp[1] = 0u; zp[2] = 0u; zp[3] = 0u;
    }
    __syncthreads();

    // layer 1: wave w -> mid-feats 16w..16w+15
#pragma unroll
    for (int nt = 0; nt < 4; nt++) {
        const unsigned* bp = Xs + (quad * 8) * 65 + nt * 16 + nl;
        bf16x8 bh, bl; frag_packed(bp, bh, bl);
        f32x4 c = {0.f, 0.f, 0.f, 0.f};
        c = MFMA(e1h, bh, c); c = MFMA(e1h, bl, c); c = MFMA(e1l, bh, c);
#pragma unroll
        for (int reg = 0; reg < 4; reg++) {
            const int fm = 16 * w + quad * 4 + reg;
            Hs[fm * 65 + nt * 16 + nl] = pack_split(fmaxf(c[reg] + e1b[fm], 0.f));
        }
    }
    __syncthreads();

    // layer 2: K=64 (2 kc)
    f32x4 a2[4];
#pragma unroll
    for (int nt = 0; nt < 4; nt++) a2[nt] = (f32x4){0.f, 0.f, 0.f, 0.f};
#pragma unroll
    for (int kc = 0; kc < 2; kc++) {
#pragma unroll
        for (int nt = 0; nt < 4; nt++) {
            const unsigned* bp = Hs + (kc * 32 + quad * 8) * 65 + nt * 16 + nl;
            bf16x8 bh, bl; frag_packed(bp, bh, bl);
            a2[nt] = MFMA(e2h[kc], bh, a2[nt]);
            a2[nt] = MFMA(e2h[kc], bl, a2[nt]);
            a2[nt] = MFMA(e2l[kc], bh, a2[nt]);
        }
    }
#pragma unroll
    for (int reg = 0; reg < 4; reg++) {
        const int f = 16 * w + quad * 4 + reg;
        const float bv = e2b[f];
#pragma unroll
        for (int nt = 0; nt < 4; nt++)
            h0[((size_t)(b * 64 + f) << 12) + row * 64 + nt * 16 + nl] =
                fmaxf(a2[nt][reg] + bv, 0.f);
    }
}

// ---- XCD-local ready-flag helpers (relaxed only: NO fences, NO cache ops) ----
__device__ inline void spin_flag(const unsigned* p) {
    int n = 0;
    while (__hip_atomic_load(p, __ATOMIC_RELAXED, __HIP_MEMORY_SCOPE_AGENT) == 0u) {
        __builtin_amdgcn_s_sleep(2);
        if (++n > (1 << 24)) break;   // ~1s safety valve: fail loud, never hang
    }
}
__device__ inline void wait_nb(const unsigned* fl, int bid, int row, int tid) {
    if (tid == 0  && row > 0)  spin_flag(fl + bid - 1);
    if (tid == 64 && row < 63) spin_flag(fl + bid + 1);
    __syncthreads();
    asm volatile("" ::: "memory");
}

// ---- GNN layer body: quarter-pipelined, drain-free barriers, single S set
//      (R13 structure verbatim, refactored into a device function) ----
template <int K, bool MEAN>
__device__ __forceinline__ void gnn_layer(
    const float* __restrict__ hb,       // hin + b*K*4096
    const ushort* __restrict__ wf, const float* __restrict__ bias,
    float* __restrict__ houtb,          // hout + b*128*4096 (unused if MEAN)
    float* __restrict__ gsum, int b,
    unsigned* AsB, int row, int tid, const float* inv)
{
    constexpr int NQ = K / 32;            // quarters of 32 planes (= one kc each)
    const int lane = tid & 63, w = tid >> 6, quad = lane >> 4, nl = lane & 15;
    const int kp = tid >> 4, nq = tid & 15;
    const int rowu = (row > 0) ? row - 1 : row;
    const int rowd = (row < 63) ? row + 1 : row;
    const float su = (row > 0) ? 1.f : 0.f;
    const float sd = (row < 63) ? 1.f : 0.f;

    const ushort* wfl = wf + lane * 8;
    f32x4 acc[4][2];
#pragma unroll
    for (int nt = 0; nt < 4; nt++) {
        acc[nt][0] = (f32x4){0.f, 0.f, 0.f, 0.f};
        acc[nt][1] = (f32x4){0.f, 0.f, 0.f, 0.f};
    }

    float4 S[6];          // ONE staging register set (24 VGPR)
    bf16x8 V[2][2];       // current quarter's weights [ftl][hi/lo]

    auto sload = [&](int q) {
#pragma unroll
        for (int it = 0; it < 2; it++) {
            const int kg = q * 32 + it * 16 + kp;
            const float* pk = hb + ((size_t)kg << 12) + nq * 4;
            S[it * 3 + 0] = *(const float4*)(pk + row * 64);
            S[it * 3 + 1] = *(const float4*)(pk + rowu * 64);
            S[it * 3 + 2] = *(const float4*)(pk + rowd * 64);
        }
    };
    auto wload = [&](int q) {
#pragma unroll
        for (int ftl = 0; ftl < 2; ftl++) {
            V[ftl][0] = *(const bf16x8*)(wfl + ((q * 8 + 2 * w + ftl) * 2) * 512);
            V[ftl][1] = *(const bf16x8*)(wfl + ((q * 8 + 2 * w + ftl) * 2 + 1) * 512);
        }
    };
    auto stage = [&](unsigned* Ab) {
#pragma unroll
        for (int it = 0; it < 2; it++) {
            const int kl = it * 16 + kp;
            const float4 c4 = S[it * 3 + 0];
            const float4 u4 = S[it * 3 + 1];
            const float4 d4 = S[it * 3 + 2];
            const float pw = __shfl_up(c4.w, 1);
            const float nx = __shfl_down(c4.x, 1);
            const float lx = (nq > 0) ? pw : 0.f;
            const float rw = (nq < 15) ? nx : 0.f;
            unsigned* ap = Ab + kl * 65 + nq * 4;
            ap[0] = pack_split((su * u4.x + sd * d4.x + lx + c4.y) * inv[0]);
            ap[1] = pack_split((su * u4.y + sd * d4.y + c4.x + c4.z) * inv[1]);
            ap[2] = pack_split((su * u4.z + sd * d4.z + c4.y + c4.w) * inv[2]);
            ap[3] = pack_split((su * u4.w + sd * d4.w + c4.z + rw) * inv[3]);
        }
    };
    auto consume = [&](const unsigned* Ab) {
#pragma unroll
        for (int nt = 0; nt < 4; nt++) {
            const unsigned* bp = Ab + (quad * 8) * 65 + nt * 16 + nl;
            bf16x8 bh, bl; frag_packed(bp, bh, bl);
            acc[nt][0] = MFMA(V[0][0], bh, acc[nt][0]);
            acc[nt][0] = MFMA(V[0][0], bl, acc[nt][0]);
            acc[nt][0] = MFMA(V[0][1], bh, acc[nt][0]);
            acc[nt][1] = MFMA(V[1][0], bh, acc[nt][1]);
            acc[nt][1] = MFMA(V[1][0], bl, acc[nt][1]);
            acc[nt][1] = MFMA(V[1][1], bh, acc[nt][1]);
        }
    };

    // prologue
    wload(0);
    sload(0);
    stage(AsB);                // drains prologue loads (once)
    sload(1);
    block_sync_lgkm();

#pragma unroll
    for (int q = 0; q < NQ; q++) {
        consume(AsB + (q & 1) * 2080);             // waits V(q): no drain
        if (q + 1 < NQ) {
            wload(q + 1);
            stage(AsB + ((q + 1) & 1) * 2080);     // waits S(q+1)
            if (q + 2 < NQ) sload(q + 2);          // S regs free after stage
            block_sync_lgkm();                     // globals stay in flight
        }
    }

    // ---- epilogue: + rowsum*bias, relu ----
    if (!MEAN) {
#pragma unroll
        for (int ftl = 0; ftl < 2; ftl++) {
            const int fb = 32 * w + 16 * ftl + quad * 4;
            const float b0 = bias[fb], b1 = bias[fb + 1], b2 = bias[fb + 2], b3 = bias[fb + 3];
#pragma unroll
            for (int nt = 0; nt < 4; nt++) {
                const int n = 16 * nt + nl;
                const int deg = (row > 0) + (row < 63) + (n > 0) + (n < 63);
                const float rs = (float)deg / ((float)deg + 1e-6f);
                float* op = houtb + ((size_t)fb << 12) + row * 64 + n;
                op[0]        = fmaxf(acc[nt][ftl][0] + rs * b0, 0.f);
                op[1u << 12] = fmaxf(acc[nt][ftl][1] + rs * b1, 0.f);
                op[2u << 12] = fmaxf(acc[nt][ftl][2] + rs * b2, 0.f);
                op[3u << 12] = fmaxf(acc[nt][ftl][3] + rs * b3, 0.f);
            }
        }
    } else {
#pragma unroll
        for (int ftl = 0; ftl < 2; ftl++) {
            const int fb = 32 * w + 16 * ftl + quad * 4;
#pragma unroll
            for (int reg = 0; reg < 4; reg++) {
                const float bv = bias[fb + reg];
                float v = 0.f;
#pragma unroll
                for (int nt = 0; nt < 4; nt++) {
                    const int n = 16 * nt + nl;
                    const int deg = (row > 0) + (row < 63) + (n > 0) + (n < 63);
                    const float rs = (float)deg / ((float)deg + 1e-6f);
                    v += fmaxf(acc[nt][ftl][reg] + rs * bv, 0.f);
                }
                v += __shfl_xor(v, 1); v += __shfl_xor(v, 2);
                v += __shfl_xor(v, 4); v += __shfl_xor(v, 8);
                if (nl == 0) atomicAdd(&gsum[b * 128 + fb + reg], v * (1.f / 4096.f));
            }
        }
    }
}

// ---- fused 3-layer GNN: one persistent block per (b,row), flag-synced ----
__global__ __launch_bounds__(256, 4) void gnn_fused_kernel(
    const float* __restrict__ h0, float* __restrict__ h1,
    float* __restrict__ h2, const ushort* __restrict__ wfb,
    const float* __restrict__ g1b, const float* __restrict__ g2b,
    const float* __restrict__ g3b, float* __restrict__ gsum,
    unsigned* __restrict__ flags)
{
    __shared__ unsigned As[2 * 2080];     // packed hi|lo, dbuf (reused per layer)
    const int tid = threadIdx.x;
    // XCD-contiguous remap: all 64 rows of a batch element on ONE XCD, so the
    // row+-1 producer->consumer dependency is same-XCD L2-visible.
    const int bid = ((blockIdx.x & 7) << 7) | (blockIdx.x >> 3);
    const int b = bid >> 6, row = bid & 63;
    const int nq = tid & 15;
    float inv[4];
#pragma unroll
    for (int i = 0; i < 4; i++) {
        const int n = nq * 4 + i;
        const int deg = (row > 0) + (row < 63) + (n > 0) + (n < 63);
        inv[i] = 1.f / ((float)deg + 1e-6f);
    }

    // layer 1 (K=64): h0 -> h1. h0 ready via prep kernel boundary.
    gnn_layer<64, false>(h0 + (size_t)b * 64 * 4096, wfb + 12288, g1b,
                         h1 + (size_t)b * 128 * 4096, nullptr, b, As, row, tid, inv);
    __syncthreads();   // emits s_waitcnt vmcnt(0): all h1 stores retired to L2
    if (tid == 0)
        __hip_atomic_store(flags + bid, 1u, __ATOMIC_RELAXED, __HIP_MEMORY_SCOPE_AGENT);
    wait_nb(flags, bid, row, tid);

    // layer 2 (K=128): h1 -> h2 (neighbor rows warm in same XCD L2)
    gnn_layer<128, false>(h1 + (size_t)b * 128 * 4096, wfb + 28672, g2b,
                          h2 + (size_t)b * 128 * 4096, nullptr, b, As, row, tid, inv);
    __syncthreads();
    if (tid == 0)
        __hip_atomic_store(flags + 1024 + bid, 1u, __ATOMIC_RELAXED, __HIP_MEMORY_SCOPE_AGENT);
    wait_nb(flags + 1024, bid, row, tid);

    // layer 3 (K=128, mean): h2 -> gsum
    gnn_layer<128, true>(h2 + (size_t)b * 128 * 4096, wfb + 61440, g3b,
                         nullptr, gsum, b, As, row, tid, inv);
}

// ---- readout: per-batch block, 2-layer MLP (fp32 vector) ----
__global__ __launch_bounds__(256) void readout_kernel(
    const float* __restrict__ gsum, const float* __restrict__ r1w,
    const float* __restrict__ r1b, const float* __restrict__ r2w,
    const float* __restrict__ r2b, float* __restrict__ out)
{
    __shared__ float gs[128];
    __shared__ float g2[256];
    const int b = blockIdx.x, tid = threadIdx.x;
    if (tid < 128) gs[tid] = gsum[b * 128 + tid];
    __syncthreads();
    float a = r1b[tid];
#pragma unroll 16
    for (int k = 0; k < 128; k++) a = fmaf(gs[k], r1w[k * 256 + tid], a);
    g2[tid] = fmaxf(a, 0.f);
    __syncthreads();
    float a2 = r2b[tid];
#pragma unroll 16
    for (int k = 0; k < 256; k++) a2 = fmaf(g2[k], r2w[k * 256 + tid], a2);
    out[b * 256 + tid] = fmaxf(a2, 0.f);
}

extern "C" void kernel_launch(void* const* d_in, const int* in_sizes, int n_in,
                              void* d_out, int out_size, void* d_ws, size_t ws_size,
                              hipStream_t stream)
{
    const float* obs = (const float*)d_in[0];
    const float* e1w = (const float*)d_in[1];
    const float* e1b = (const float*)d_in[2];
    const float* e2w = (const float*)d_in[3];
    const float* e2b = (const float*)d_in[4];
    const float* g1w = (const float*)d_in[5];
    const float* g1b = (const float*)d_in[6];
    const float* g2w = (const float*)d_in[7];
    const float* g2b = (const float*)d_in[8];
    const float* g3w = (const float*)d_in[9];
    const float* g3b = (const float*)d_in[10];
    const float* r1w = (const float*)d_in[11];
    const float* r1b = (const float*)d_in[12];
    const float* r2w = (const float*)d_in[13];
    const float* r2b = (const float*)d_in[14];
    float* out = (float*)d_out;
    float* ws = (float*)d_ws;

    float* h0 = ws;                                   // 16 MB
    float* h1 = ws + 4194304;                         // 32 MB
    float* h2 = ws + 4194304 + 8388608;               // 32 MB
    float* gsum = (float*)((char*)d_ws + 80u * 1024u * 1024u);          // 8 KB
    ushort* wfb = (ushort*)((char*)d_ws + 80u * 1024u * 1024u + 8192u); // 184 KB
    unsigned* flags = (unsigned*)((char*)d_ws + 80u * 1024u * 1024u + 8192u + 196608u); // 8 KB

    hipLaunchKernelGGL(prep_embed_kernel, dim3(1060), dim3(256), 0, stream,
                       obs, e1w, e1b, e2w, e2b, g1w, g2w, g3w, wfb, gsum, h0, flags);
    hipLaunchKernelGGL(gnn_fused_kernel, dim3(1024), dim3(256), 0, stream,
                       h0, h1, h2, wfb, g1b, g2b, g3b, gsum, flags);
    hipLaunchKernelGGL(readout_kernel, dim3(16), dim3(256), 0, stream,
                       gsum, r1w, r1b, r2w, r2b, out);
}

// Round 3
// 159.562 us; speedup vs baseline: 1.1508x; 1.1508x over previous
//
#include <hip/hip_runtime.h>

// R20 = R19 with the LDS overrun fixed (lds[4160] -> lds[6240]; Hs alone
// needs 64*65=4160 entries at offset 2080 -- R19 wrote 2KB past the
// allocation -> absmax 0.103). R19's structural changes retained:
//   1. e1/e2 weight fragments built DIRECT from global (20KB, L1-resident
//      after first block) -- removes the per-block 20KB LDS restage and 2 of
//      4 barrier phases.
//   2. aux work (g-weight prep, gsum zero) folded into the first 28 embed
//      blocks; grid exactly 1024 = one resident generation (was 1052).
//      Aux outputs are consumed only by LATER launches: no intra-kernel
//      ordering assumed.
// R18 post-mortem: fusing the 3 GNN launches via XCD-local flags REGRESSED
// (79us fused vs ~60-65us separate: per-XCD h1 share = 4MB = full L2,
// self-evicting; no reuse). GNN stays 3-launch R13 structure -- seventeen
// structural variants bracket it.
//
// Intermediates FEATURE-MAJOR h[b][f][n], n = 64x64 grid.
// GNN layer exact rewrite: h' = relu( agg(h) @ W + rowsum*b ).
// fp32 split a = hi + lo (bf16); 3 MFMAs: hi*wh + hi*wl + lo*wh.
//
// MFMA 16x16x32 bf16 layouts (verified m89/m120):
//   A (MxK): m = lane&15, k = quad*8 + j    B (KxN): n = lane&15, k = quad*8 + j
//   C/D: col(N) = lane&15, row(M) = quad*4 + reg

typedef __attribute__((ext_vector_type(8))) short bf16x8;
typedef __attribute__((ext_vector_type(4))) float f32x4;
#define MFMA(a, b, c) __builtin_amdgcn_mfma_f32_16x16x32_bf16(a, b, c, 0, 0, 0)

// barrier with LDS visibility but WITHOUT draining global loads:
// s_waitcnt imm 0xC07F = vmcnt(63) expcnt(7) lgkmcnt(0)
__device__ inline void block_sync_lgkm() {
    asm volatile("" ::: "memory");
    __builtin_amdgcn_s_waitcnt(0xC07F);
    __builtin_amdgcn_s_barrier();
    asm volatile("" ::: "memory");
}

__device__ inline ushort bf16h(float x) {
    unsigned u = __float_as_uint(x);
    return (ushort)((u + 0x7fffu + ((u >> 16) & 1u)) >> 16);
}
__device__ inline void split_bf16(float x, ushort& hi, ushort& lo) {
    hi = bf16h(x);
    lo = bf16h(x - __uint_as_float(((unsigned)hi) << 16));
}
// packed (hi16 << 16) | lo16 ; hi = RNE, lo = truncation
__device__ inline unsigned pack_split(float x) {
    unsigned u = __float_as_uint(x);
    unsigned hi = (u + 0x7fffu + ((u >> 16) & 1u)) >> 16;
    float r = x - __uint_as_float(hi << 16);
    return (hi << 16) | (__float_as_uint(r) >> 16);
}
// 8 packed u32 (stride 65) -> hi/lo bf16x8 fragments
__device__ inline void frag_packed(const unsigned* bp, bf16x8& bh, bf16x8& bl) {
    unsigned p[8];
#pragma unroll
    for (int j = 0; j < 8; j++) p[j] = bp[j * 65];
    union { bf16x8 v; unsigned d[4]; } H, L;
#pragma unroll
    for (int j = 0; j < 4; j++) {
        const unsigned e = p[2 * j], o = p[2 * j + 1];
        H.d[j] = (o & 0xFFFF0000u) | (e >> 16);
        L.d[j] = (o << 16) | (e & 0xFFFFu);
    }
    bh = H.v; bl = L.v;
}

// ---- launch 1: embed (1024 blocks); aux work folded into first 28 blocks ----
// g-frag unit (kc,t) = 2 planes x 512 ushorts; per layer unit idx = kc*8 + t.
// wfb ushort offsets: g1@12288 (16 units), g2@28672 (32), g3@61440 (32).
__global__ __launch_bounds__(256, 4) void prep_embed_kernel(
    const float* __restrict__ obs,
    const float* __restrict__ e1w, const float* __restrict__ e1b,
    const float* __restrict__ e2w, const float* __restrict__ e2b,
    const float* __restrict__ g1w, const float* __restrict__ g2w,
    const float* __restrict__ g3w, ushort* __restrict__ wf,
    float* __restrict__ gsum, float* __restrict__ h0)
{
    const int blk = blockIdx.x, tid = threadIdx.x;

    // ---- aux: g-weight prep (blk<20, 4 units/block) + gsum zero (blk<28).
    // Outputs consumed only by LATER launches -> no intra-kernel ordering.
    if (blk < 20) {
        const int u = blk * 4 + (tid >> 6);
        const int l = tid & 63;
        const float* src; int K, kc, t; ushort* dst;
        if (u < 16)      { src = g1w; K = 64;  kc = u >> 3;        t = u & 7; dst = wf + 12288; }
        else if (u < 48) { src = g2w; K = 128; kc = (u - 16) >> 3; t = (u - 16) & 7; dst = wf + 28672; }
        else             { src = g3w; K = 128; kc = (u - 48) >> 3; t = (u - 48) & 7; dst = wf + 61440; }
        ushort* uh = dst + ((kc * 8 + t) * 2 + 0) * 512 + l * 8;
        ushort* ul = dst + ((kc * 8 + t) * 2 + 1) * 512 + l * 8;
        const int fw = t * 16 + (l & 15);
        const int kb = kc * 32 + ((l >> 4) << 3);
#pragma unroll
        for (int j = 0; j < 8; j++) {
            const int k = kb + j;
            const float wv = (k < K) ? src[k * 128 + fw] : 0.f;
            ushort hi, lo; split_bf16(wv, hi, lo);
            uh[j] = hi; ul[j] = lo;
        }
    } else if (blk < 28) {
        gsum[(blk - 20) * 256 + tid] = 0.f;
    }

    // ---- embed: block = (b, row) = 64 nodes, fused 2-layer MLP via MFMA ----
    __shared__ unsigned lds[6240];         // Xs = lds[0..2080), Hs = lds+2080 (4160)
    // XCD remap ALIGNED with gnn readers: h0 rows land on the XCD that reads them
    const int ebid = ((blk & 7) << 7) | (blk >> 3);
    const int b = ebid >> 6, row = ebid & 63;
    const int lane = tid & 63, w = tid >> 6, quad = lane >> 4, nl = lane & 15;
    const int cp = tid >> 4, nq = tid & 15;

    // obs load issued early (used in phase X)
    const float4 x4 = *(const float4*)(obs + ((size_t)(b * 16 + cp) << 12) + row * 64 + nq * 4);

    // weight fragments DIRECT from global (e1w 4KB + e2w 16KB, L1-resident
    // after the first block on each CU; 64B-per-quad coalesced segments)
    float e1f[8], e2f[16];
    {
        const int f = 16 * w + nl;
#pragma unroll
        for (int j = 0; j < 8; j++) {
            const int k = quad * 8 + j;
            e1f[j] = (k < 16) ? e1w[k * 64 + f] : 0.f;
        }
#pragma unroll
        for (int kc = 0; kc < 2; kc++)
#pragma unroll
            for (int j = 0; j < 8; j++)
                e2f[kc * 8 + j] = e2w[(kc * 32 + quad * 8 + j) * 64 + f];
    }

    // phase X: stage obs packed (B-operand planes, k>=16 zeroed)
    unsigned* Xs = lds;
    unsigned* Hs = lds + 2080;
    {
        unsigned* xp = Xs + cp * 65 + nq * 4;
        xp[0] = pack_split(x4.x); xp[1] = pack_split(x4.y);
        xp[2] = pack_split(x4.z); xp[3] = pack_split(x4.w);
        unsigned* zp = Xs + (16 + cp) * 65 + nq * 4;
        zp[0] = 0u; zp[1] = 0u; zp[2] = 0u; zp[3] = 0u;
    }

    // build this wave's weight fragments in registers (A-operand, M=feats);
    // VALU-only, overlaps the weight-load latency before the barrier
    bf16x8 e1h, e1l, e2h[2], e2l[2];
#pragma unroll
    for (int j = 0; j < 8; j++) {
        ushort hi, lo; split_bf16(e1f[j], hi, lo);
        e1h[j] = (short)hi; e1l[j] = (short)lo;
    }
#pragma unroll
    for (int kc = 0; kc < 2; kc++)
#pragma unroll
        for (int j = 0; j < 8; j++) {
            ushort hi, lo; split_bf16(e2f[kc * 8 + j], hi, lo);
            e2h[kc][j] = (short)hi; e2l[kc][j] = (short)lo;
        }
    __syncthreads();

    // layer 1: wave w -> mid-feats 16w..16w+15
#pragma unroll
    for (int nt = 0; nt < 4; nt++) {
        const unsigned* bp = Xs + (quad * 8) * 65 + nt * 16 + nl;
        bf16x8 bh, bl; frag_packed(bp, bh, bl);
        f32x4 c = {0.f, 0.f, 0.f, 0.f};
        c = MFMA(e1h, bh, c); c = MFMA(e1h, bl, c); c = MFMA(e1l, bh, c);
#pragma unroll
        for (int reg = 0; reg < 4; reg++) {
            const int fm = 16 * w + quad * 4 + reg;
            Hs[fm * 65 + nt * 16 + nl] = pack_split(fmaxf(c[reg] + e1b[fm], 0.f));
        }
    }
    __syncthreads();

    // layer 2: K=64 (2 kc)
    f32x4 a2[4];
#pragma unroll
    for (int nt = 0; nt < 4; nt++) a2[nt] = (f32x4){0.f, 0.f, 0.f, 0.f};
#pragma unroll
    for (int kc = 0; kc < 2; kc++) {
#pragma unroll
        for (int nt = 0; nt < 4; nt++) {
            const unsigned* bp = Hs + (kc * 32 + quad * 8) * 65 + nt * 16 + nl;
            bf16x8 bh, bl; frag_packed(bp, bh, bl);
            a2[nt] = MFMA(e2h[kc], bh, a2[nt]);
            a2[nt] = MFMA(e2h[kc], bl, a2[nt]);
            a2[nt] = MFMA(e2l[kc], bh, a2[nt]);
        }
    }
#pragma unroll
    for (int reg = 0; reg < 4; reg++) {
        const int f = 16 * w + quad * 4 + reg;
        const float bv = e2b[f];
#pragma unroll
        for (int nt = 0; nt < 4; nt++)
            h0[((size_t)(b * 64 + f) << 12) + row * 64 + nt * 16 + nl] =
                fmaxf(a2[nt][reg] + bv, 0.f);
    }
}

// ---- GNN layer: quarter-pipelined, drain-free barriers, single S set ----
template <int K, bool MEAN>
__global__ __launch_bounds__(256, 4) void gnn_kernel(
    const float* __restrict__ hin, const ushort* __restrict__ wf,
    const float* __restrict__ bias, float* __restrict__ hout,
    float* __restrict__ gsum)
{
    constexpr int NQ = K / 32;            // quarters of 32 planes (= one kc each)
    __shared__ unsigned As[2][32 * 65];   // packed hi|lo, dbuf
    const int tid = threadIdx.x;
    // XCD-contiguous remap: consecutive rows on the same XCD (R7: FETCH 49->18MB)
    const int bid = ((blockIdx.x & 7) << 7) | (blockIdx.x >> 3);
    const int b = bid >> 6, row = bid & 63;
    const int lane = tid & 63, w = tid >> 6, quad = lane >> 4, nl = lane & 15;
    const int kp = tid >> 4, nq = tid & 15;
    const float* hb = hin + (size_t)b * K * 4096;
    const int rowu = (row > 0) ? row - 1 : row;
    const int rowd = (row < 63) ? row + 1 : row;
    const float su = (row > 0) ? 1.f : 0.f;
    const float sd = (row < 63) ? 1.f : 0.f;
    float inv[4];
#pragma unroll
    for (int i = 0; i < 4; i++) {
        const int n = nq * 4 + i;
        const int deg = (row > 0) + (row < 63) + (n > 0) + (n < 63);
        inv[i] = 1.f / ((float)deg + 1e-6f);
    }

    const ushort* wfl = wf + lane * 8;
    f32x4 acc[4][2];
#pragma unroll
    for (int nt = 0; nt < 4; nt++) {
        acc[nt][0] = (f32x4){0.f, 0.f, 0.f, 0.f};
        acc[nt][1] = (f32x4){0.f, 0.f, 0.f, 0.f};
    }

    float4 S[6];          // ONE staging register set (24 VGPR)
    bf16x8 V[2][2];       // current quarter's weights [ftl][hi/lo]

    auto sload = [&](int q) {
#pragma unroll
        for (int it = 0; it < 2; it++) {
            const int kg = q * 32 + it * 16 + kp;
            const float* pk = hb + ((size_t)kg << 12) + nq * 4;
            S[it * 3 + 0] = *(const float4*)(pk + row * 64);
            S[it * 3 + 1] = *(const float4*)(pk + rowu * 64);
            S[it * 3 + 2] = *(const float4*)(pk + rowd * 64);
        }
    };
    auto wload = [&](int q) {
#pragma unroll
        for (int ftl = 0; ftl < 2; ftl++) {
            V[ftl][0] = *(const bf16x8*)(wfl + ((q * 8 + 2 * w + ftl) * 2) * 512);
            V[ftl][1] = *(const bf16x8*)(wfl + ((q * 8 + 2 * w + ftl) * 2 + 1) * 512);
        }
    };
    auto stage = [&](unsigned* Ab) {
#pragma unroll
        for (int it = 0; it < 2; it++) {
            const int kl = it * 16 + kp;
            const float4 c4 = S[it * 3 + 0];
            const float4 u4 = S[it * 3 + 1];
            const float4 d4 = S[it * 3 + 2];
            const float pw = __shfl_up(c4.w, 1);
            const float nx = __shfl_down(c4.x, 1);
            const float lx = (nq > 0) ? pw : 0.f;
            const float rw = (nq < 15) ? nx : 0.f;
            unsigned* ap = Ab + kl * 65 + nq * 4;
            ap[0] = pack_split((su * u4.x + sd * d4.x + lx + c4.y) * inv[0]);
            ap[1] = pack_split((su * u4.y + sd * d4.y + c4.x + c4.z) * inv[1]);
            ap[2] = pack_split((su * u4.z + sd * d4.z + c4.y + c4.w) * inv[2]);
            ap[3] = pack_split((su * u4.w + sd * d4.w + c4.z + rw) * inv[3]);
        }
    };
    auto consume = [&](const unsigned* Ab) {
#pragma unroll
        for (int nt = 0; nt < 4; nt++) {
            const unsigned* bp = Ab + (quad * 8) * 65 + nt * 16 + nl;
            bf16x8 bh, bl; frag_packed(bp, bh, bl);
            acc[nt][0] = MFMA(V[0][0], bh, acc[nt][0]);
            acc[nt][0] = MFMA(V[0][0], bl, acc[nt][0]);
            acc[nt][0] = MFMA(V[0][1], bh, acc[nt][0]);
            acc[nt][1] = MFMA(V[1][0], bh, acc[nt][1]);
            acc[nt][1] = MFMA(V[1][0], bl, acc[nt][1]);
            acc[nt][1] = MFMA(V[1][1], bh, acc[nt][1]);
        }
    };

    // prologue
    wload(0);
    sload(0);
    stage(As[0]);              // drains prologue loads (once)
    sload(1);
    block_sync_lgkm();

#pragma unroll
    for (int q = 0; q < NQ; q++) {
        consume(As[q & 1]);                    // waits V(q): vmcnt<=6, no drain
        if (q + 1 < NQ) {
            wload(q + 1);
            stage(As[(q + 1) & 1]);            // waits S(q+1): vmcnt<=4
            if (q + 2 < NQ) sload(q + 2);      // S regs free after stage
            block_sync_lgkm();                 // globals stay in flight
        }
    }

    // ---- epilogue: + rowsum*bias, relu ----
    if (!MEAN) {
#pragma unroll
        for (int ftl = 0; ftl < 2; ftl++) {
            const int fb = 32 * w + 16 * ftl + quad * 4;
            const float b0 = bias[fb], b1 = bias[fb + 1], b2 = bias[fb + 2], b3 = bias[fb + 3];
#pragma unroll
            for (int nt = 0; nt < 4; nt++) {
                const int n = 16 * nt + nl;
                const int deg = (row > 0) + (row < 63) + (n > 0) + (n < 63);
                const float rs = (float)deg / ((float)deg + 1e-6f);
                float* op = hout + ((size_t)(b * 128 + fb) << 12) + row * 64 + n;
                op[0]        = fmaxf(acc[nt][ftl][0] + rs * b0, 0.f);
                op[1u << 12] = fmaxf(acc[nt][ftl][1] + rs * b1, 0.f);
                op[2u << 12] = fmaxf(acc[nt][ftl][2] + rs * b2, 0.f);
                op[3u << 12] = fmaxf(acc[nt][ftl][3] + rs * b3, 0.f);
            }
        }
    } else {
#pragma unroll
        for (int ftl = 0; ftl < 2; ftl++) {
            const int fb = 32 * w + 16 * ftl + quad * 4;
#pragma unroll
            for (int reg = 0; reg < 4; reg++) {
                const float bv = bias[fb + reg];
                float v = 0.f;
#pragma unroll
                for (int nt = 0; nt < 4; nt++) {
                    const int n = 16 * nt + nl;
                    const int deg = (row > 0) + (row < 63) + (n > 0) + (n < 63);
                    const float rs = (float)deg / ((float)deg + 1e-6f);
                    v += fmaxf(acc[nt][ftl][reg] + rs * bv, 0.f);
                }
                v += __shfl_xor(v, 1); v += __shfl_xor(v, 2);
                v += __shfl_xor(v, 4); v += __shfl_xor(v, 8);
                if (nl == 0) atomicAdd(&gsum[b * 128 + fb + reg], v * (1.f / 4096.f));
            }
        }
    }
}

// ---- readout: per-batch block, 2-layer MLP (fp32 vector) ----
__global__ __launch_bounds__(256) void readout_kernel(
    const float* __restrict__ gsum, const float* __restrict__ r1w,
    const float* __restrict__ r1b, const float* __restrict__ r2w,
    const float* __restrict__ r2b, float* __restrict__ out)
{
    __shared__ float gs[128];
    __shared__ float g2[256];
    const int b = blockIdx.x, tid = threadIdx.x;
    if (tid < 128) gs[tid] = gsum[b * 128 + tid];
    __syncthreads();
    float a = r1b[tid];
#pragma unroll 16
    for (int k = 0; k < 128; k++) a = fmaf(gs[k], r1w[k * 256 + tid], a);
    g2[tid] = fmaxf(a, 0.f);
    __syncthreads();
    float a2 = r2b[tid];
#pragma unroll 16
    for (int k = 0; k < 256; k++) a2 = fmaf(g2[k], r2w[k * 256 + tid], a2);
    out[b * 256 + tid] = fmaxf(a2, 0.f);
}

extern "C" void kernel_launch(void* const* d_in, const int* in_sizes, int n_in,
                              void* d_out, int out_size, void* d_ws, size_t ws_size,
                              hipStream_t stream)
{
    const float* obs = (const float*)d_in[0];
    const float* e1w = (const float*)d_in[1];
    const float* e1b = (const float*)d_in[2];
    const float* e2w = (const float*)d_in[3];
    const float* e2b = (const float*)d_in[4];
    const float* g1w = (const float*)d_in[5];
    const float* g1b = (const float*)d_in[6];
    const float* g2w = (const float*)d_in[7];
    const float* g2b = (const float*)d_in[8];
    const float* g3w = (const float*)d_in[9];
    const float* g3b = (const float*)d_in[10];
    const float* r1w = (const float*)d_in[11];
    const float* r1b = (const float*)d_in[12];
    const float* r2w = (const float*)d_in[13];
    const float* r2b = (const float*)d_in[14];
    float* out = (float*)d_out;
    float* ws = (float*)d_ws;

    float* h0 = ws;                                   // 16 MB
    float* h1 = ws + 4194304;                         // 32 MB
    float* h2 = ws + 4194304 + 8388608;               // 32 MB
    float* gsum = (float*)((char*)d_ws + 80u * 1024u * 1024u);          // 8 KB
    ushort* wfb = (ushort*)((char*)d_ws + 80u * 1024u * 1024u + 8192u); // 184 KB

    hipLaunchKernelGGL(prep_embed_kernel, dim3(1024), dim3(256), 0, stream,
                       obs, e1w, e1b, e2w, e2b, g1w, g2w, g3w, wfb, gsum, h0);
    hipLaunchKernelGGL((gnn_kernel<64, false>), dim3(1024), dim3(256), 0, stream,
                       h0, wfb + 12288, g1b, h1, nullptr);
    hipLaunchKernelGGL((gnn_kernel<128, false>), dim3(1024), dim3(256), 0, stream,
                       h1, wfb + 28672, g2b, h2, nullptr);
    hipLaunchKernelGGL((gnn_kernel<128, true>), dim3(1024), dim3(256), 0, stream,
                       h2, wfb + 61440, g3b, nullptr, gsum);
    hipLaunchKernelGGL(readout_kernel, dim3(16), dim3(256), 0, stream,
                       gsum, r1w, r1b, r2w, r2b, out);
}

// Round 4
// 149.833 us; speedup vs baseline: 1.2255x; 1.0649x over previous
//
#include <hip/hip_runtime.h>

// R21 = R20 with BF16 intermediates (h0/h1/h2 stored as bf16, was f32).
// Rationale: the ~112us non-fill time is a latency-exposure plateau
// (MfmaUtil ~4-8%, VALUBusy ~13-17%, hbm ~30%): gnn sload(q+1) is issued
// only ONE compute phase (~400cy) before stage(q+1) waits, vs ~900-1900cy
// HBM latency. bf16 h halves the sload instruction count (3 float4 cover a
// full 32-plane quarter), so the SAME 24-VGPR S budget holds TWO quarters
// in flight -> loads issue TWO compute phases ahead. Also halves gnn HBM
// traffic (reads 80->40MB, writes 64->32MB). Precision: one extra rounding
// per layer (rel 2^-9), independent per (f,n), shrunk x64 by the final
// node-mean -> predicted absmax ~5e-4 vs 4.375e-3 threshold. Aggregation
// stays fp32; hi/lo split of the AGGREGATE + 3-MFMA scheme unchanged.
// History: R18 gnn-fusion regressed (L2 self-eviction); R19 LDS overrun
// (fixed in R20); R20 prep restructure neutral (kept: simpler, 1024 grid).
// Seventeen structural variants bracket the R13 gnn design.
//
// Intermediates FEATURE-MAJOR h[b][f][n] (bf16), n = 64x64 grid.
// GNN layer exact rewrite: h' = relu( agg(h) @ W + rowsum*b ).
// fp32 aggregate a = hi + lo (bf16); 3 MFMAs: hi*wh + hi*wl + lo*wh.
//
// MFMA 16x16x32 bf16 layouts (verified m89/m120):
//   A (MxK): m = lane&15, k = quad*8 + j    B (KxN): n = lane&15, k = quad*8 + j
//   C/D: col(N) = lane&15, row(M) = quad*4 + reg

typedef __attribute__((ext_vector_type(8))) short bf16x8;
typedef __attribute__((ext_vector_type(4))) float f32x4;
#define MFMA(a, b, c) __builtin_amdgcn_mfma_f32_16x16x32_bf16(a, b, c, 0, 0, 0)

// barrier with LDS visibility but WITHOUT draining global loads:
// s_waitcnt imm 0xC07F = vmcnt(63) expcnt(7) lgkmcnt(0)
__device__ inline void block_sync_lgkm() {
    asm volatile("" ::: "memory");
    __builtin_amdgcn_s_waitcnt(0xC07F);
    __builtin_amdgcn_s_barrier();
    asm volatile("" ::: "memory");
}

__device__ inline ushort bf16h(float x) {
    unsigned u = __float_as_uint(x);
    return (ushort)((u + 0x7fffu + ((u >> 16) & 1u)) >> 16);
}
__device__ inline void split_bf16(float x, ushort& hi, ushort& lo) {
    hi = bf16h(x);
    lo = bf16h(x - __uint_as_float(((unsigned)hi) << 16));
}
// packed (hi16 << 16) | lo16 ; hi = RNE, lo = truncation
__device__ inline unsigned pack_split(float x) {
    unsigned u = __float_as_uint(x);
    unsigned hi = (u + 0x7fffu + ((u >> 16) & 1u)) >> 16;
    float r = x - __uint_as_float(hi << 16);
    return (hi << 16) | (__float_as_uint(r) >> 16);
}
// bf16 pair in a u32: even node = low ushort, odd node = high ushort
__device__ inline float bflo(unsigned w) { return __uint_as_float(w << 16); }
__device__ inline float bfhi(unsigned w) { return __uint_as_float(w & 0xFFFF0000u); }
// 8 packed u32 (stride 65) -> hi/lo bf16x8 fragments
__device__ inline void frag_packed(const unsigned* bp, bf16x8& bh, bf16x8& bl) {
    unsigned p[8];
#pragma unroll
    for (int j = 0; j < 8; j++) p[j] = bp[j * 65];
    union { bf16x8 v; unsigned d[4]; } H, L;
#pragma unroll
    for (int j = 0; j < 4; j++) {
        const unsigned e = p[2 * j], o = p[2 * j + 1];
        H.d[j] = (o & 0xFFFF0000u) | (e >> 16);
        L.d[j] = (o << 16) | (e & 0xFFFFu);
    }
    bh = H.v; bl = L.v;
}

// ---- launch 1: embed (1024 blocks); aux work folded into first 28 blocks ----
// g-frag unit (kc,t) = 2 planes x 512 ushorts; per layer unit idx = kc*8 + t.
// wfb ushort offsets: g1@12288 (16 units), g2@28672 (32), g3@61440 (32).
__global__ __launch_bounds__(256, 4) void prep_embed_kernel(
    const float* __restrict__ obs,
    const float* __restrict__ e1w, const float* __restrict__ e1b,
    const float* __restrict__ e2w, const float* __restrict__ e2b,
    const float* __restrict__ g1w, const float* __restrict__ g2w,
    const float* __restrict__ g3w, ushort* __restrict__ wf,
    float* __restrict__ gsum, ushort* __restrict__ h0)
{
    const int blk = blockIdx.x, tid = threadIdx.x;

    // ---- aux: g-weight prep (blk<20, 4 units/block) + gsum zero (blk<28).
    // Outputs consumed only by LATER launches -> no intra-kernel ordering.
    if (blk < 20) {
        const int u = blk * 4 + (tid >> 6);
        const int l = tid & 63;
        const float* src; int K, kc, t; ushort* dst;
        if (u < 16)      { src = g1w; K = 64;  kc = u >> 3;        t = u & 7; dst = wf + 12288; }
        else if (u < 48) { src = g2w; K = 128; kc = (u - 16) >> 3; t = (u - 16) & 7; dst = wf + 28672; }
        else             { src = g3w; K = 128; kc = (u - 48) >> 3; t = (u - 48) & 7; dst = wf + 61440; }
        ushort* uh = dst + ((kc * 8 + t) * 2 + 0) * 512 + l * 8;
        ushort* ul = dst + ((kc * 8 + t) * 2 + 1) * 512 + l * 8;
        const int fw = t * 16 + (l & 15);
        const int kb = kc * 32 + ((l >> 4) << 3);
#pragma unroll
        for (int j = 0; j < 8; j++) {
            const int k = kb + j;
            const float wv = (k < K) ? src[k * 128 + fw] : 0.f;
            ushort hi, lo; split_bf16(wv, hi, lo);
            uh[j] = hi; ul[j] = lo;
        }
    } else if (blk < 28) {
        gsum[(blk - 20) * 256 + tid] = 0.f;
    }

    // ---- embed: block = (b, row) = 64 nodes, fused 2-layer MLP via MFMA ----
    __shared__ unsigned lds[6240];         // Xs = lds[0..2080), Hs = lds+2080 (4160)
    // XCD remap ALIGNED with gnn readers: h0 rows land on the XCD that reads them
    const int ebid = ((blk & 7) << 7) | (blk >> 3);
    const int b = ebid >> 6, row = ebid & 63;
    const int lane = tid & 63, w = tid >> 6, quad = lane >> 4, nl = lane & 15;
    const int cp = tid >> 4, nq = tid & 15;

    // obs load issued early (used in phase X)
    const float4 x4 = *(const float4*)(obs + ((size_t)(b * 16 + cp) << 12) + row * 64 + nq * 4);

    // weight fragments DIRECT from global (e1w 4KB + e2w 16KB, L1-resident
    // after the first block on each CU; 64B-per-quad coalesced segments)
    float e1f[8], e2f[16];
    {
        const int f = 16 * w + nl;
#pragma unroll
        for (int j = 0; j < 8; j++) {
            const int k = quad * 8 + j;
            e1f[j] = (k < 16) ? e1w[k * 64 + f] : 0.f;
        }
#pragma unroll
        for (int kc = 0; kc < 2; kc++)
#pragma unroll
            for (int j = 0; j < 8; j++)
                e2f[kc * 8 + j] = e2w[(kc * 32 + quad * 8 + j) * 64 + f];
    }

    // phase X: stage obs packed (B-operand planes, k>=16 zeroed)
    unsigned* Xs = lds;
    unsigned* Hs = lds + 2080;
    {
        unsigned* xp = Xs + cp * 65 + nq * 4;
        xp[0] = pack_split(x4.x); xp[1] = pack_split(x4.y);
        xp[2] = pack_split(x4.z); xp[3] = pack_split(x4.w);
        unsigned* zp = Xs + (16 + cp) * 65 + nq * 4;
        zp[0] = 0u; zp[1] = 0u; zp[2] = 0u; zp[3] = 0u;
    }

    // build this wave's weight fragments in registers (A-operand, M=feats);
    // VALU-only, overlaps the weight-load latency before the barrier
    bf16x8 e1h, e1l, e2h[2], e2l[2];
#pragma unroll
    for (int j = 0; j < 8; j++) {
        ushort hi, lo; split_bf16(e1f[j], hi, lo);
        e1h[j] = (short)hi; e1l[j] = (short)lo;
    }
#pragma unroll
    for (int kc = 0; kc < 2; kc++)
#pragma unroll
        for (int j = 0; j < 8; j++) {
            ushort hi, lo; split_bf16(e2f[kc * 8 + j], hi, lo);
            e2h[kc][j] = (short)hi; e2l[kc][j] = (short)lo;
        }
    __syncthreads();

    // layer 1: wave w -> mid-feats 16w..16w+15
#pragma unroll
    for (int nt = 0; nt < 4; nt++) {
        const unsigned* bp = Xs + (quad * 8) * 65 + nt * 16 + nl;
        bf16x8 bh, bl; frag_packed(bp, bh, bl);
        f32x4 c = {0.f, 0.f, 0.f, 0.f};
        c = MFMA(e1h, bh, c); c = MFMA(e1h, bl, c); c = MFMA(e1l, bh, c);
#pragma unroll
        for (int reg = 0; reg < 4; reg++) {
            const int fm = 16 * w + quad * 4 + reg;
            Hs[fm * 65 + nt * 16 + nl] = pack_split(fmaxf(c[reg] + e1b[fm], 0.f));
        }
    }
    __syncthreads();

    // layer 2: K=64 (2 kc)
    f32x4 a2[4];
#pragma unroll
    for (int nt = 0; nt < 4; nt++) a2[nt] = (f32x4){0.f, 0.f, 0.f, 0.f};
#pragma unroll
    for (int kc = 0; kc < 2; kc++) {
#pragma unroll
        for (int nt = 0; nt < 4; nt++) {
            const unsigned* bp = Hs + (kc * 32 + quad * 8) * 65 + nt * 16 + nl;
            bf16x8 bh, bl; frag_packed(bp, bh, bl);
            a2[nt] = MFMA(e2h[kc], bh, a2[nt]);
            a2[nt] = MFMA(e2h[kc], bl, a2[nt]);
            a2[nt] = MFMA(e2l[kc], bh, a2[nt]);
        }
    }
#pragma unroll
    for (int reg = 0; reg < 4; reg++) {
        const int f = 16 * w + quad * 4 + reg;
        const float bv = e2b[f];
#pragma unroll
        for (int nt = 0; nt < 4; nt++)
            h0[((size_t)(b * 64 + f) << 12) + row * 64 + nt * 16 + nl] =
                bf16h(fmaxf(a2[nt][reg] + bv, 0.f));
    }
}

// ---- GNN layer: bf16 input, 2-quarter-deep pipeline, drain-free barriers ----
template <int K, bool MEAN>
__global__ __launch_bounds__(256, 4) void gnn_kernel(
    const ushort* __restrict__ hin, const ushort* __restrict__ wf,
    const float* __restrict__ bias, ushort* __restrict__ hout,
    float* __restrict__ gsum)
{
    constexpr int NQ = K / 32;            // quarters of 32 planes (= one kc each)
    __shared__ unsigned As[2][32 * 65];   // packed hi|lo, dbuf
    const int tid = threadIdx.x;
    // XCD-contiguous remap: consecutive rows on the same XCD (R7: FETCH 49->18MB)
    const int bid = ((blockIdx.x & 7) << 7) | (blockIdx.x >> 3);
    const int b = bid >> 6, row = bid & 63;
    const int lane = tid & 63, w = tid >> 6, quad = lane >> 4, nl = lane & 15;
    const int kp8 = tid >> 3, nq8 = tid & 7;   // plane 0-31, 8-node group
    const ushort* hb = hin + (size_t)b * K * 4096;
    const int rowu = (row > 0) ? row - 1 : row;
    const int rowd = (row < 63) ? row + 1 : row;
    const float su = (row > 0) ? 1.f : 0.f;
    const float sd = (row < 63) ? 1.f : 0.f;
    float inv8[8];
#pragma unroll
    for (int i = 0; i < 8; i++) {
        const int n = nq8 * 8 + i;
        const int deg = (row > 0) + (row < 63) + (n > 0) + (n < 63);
        inv8[i] = 1.f / ((float)deg + 1e-6f);
    }

    const ushort* wfl = wf + lane * 8;
    f32x4 acc[4][2];
#pragma unroll
    for (int nt = 0; nt < 4; nt++) {
        acc[nt][0] = (f32x4){0.f, 0.f, 0.f, 0.f};
        acc[nt][1] = (f32x4){0.f, 0.f, 0.f, 0.f};
    }

    float4 S[6];          // TWO staging sets (bf16: one quarter = 3 float4)
    bf16x8 V[2][2];       // current quarter's weights [ftl][hi/lo]

    auto sload = [&](int q, int s) {      // one quarter = 32 planes, 3 loads
        const int kg = q * 32 + kp8;
        const ushort* pk = hb + ((size_t)kg << 12) + nq8 * 8;
        S[s * 3 + 0] = *(const float4*)(pk + row * 64);
        S[s * 3 + 1] = *(const float4*)(pk + rowu * 64);
        S[s * 3 + 2] = *(const float4*)(pk + rowd * 64);
    };
    auto wload = [&](int q) {
#pragma unroll
        for (int ftl = 0; ftl < 2; ftl++) {
            V[ftl][0] = *(const bf16x8*)(wfl + ((q * 8 + 2 * w + ftl) * 2) * 512);
            V[ftl][1] = *(const bf16x8*)(wfl + ((q * 8 + 2 * w + ftl) * 2 + 1) * 512);
        }
    };
    auto stage = [&](unsigned* Ab, int s) {
        const float4 c4 = S[s * 3 + 0];
        const float4 u4 = S[s * 3 + 1];
        const float4 d4 = S[s * 3 + 2];
        const unsigned cw[4] = {__float_as_uint(c4.x), __float_as_uint(c4.y),
                                __float_as_uint(c4.z), __float_as_uint(c4.w)};
        const unsigned uw[4] = {__float_as_uint(u4.x), __float_as_uint(u4.y),
                                __float_as_uint(u4.z), __float_as_uint(u4.w)};
        const unsigned dw[4] = {__float_as_uint(d4.x), __float_as_uint(d4.y),
                                __float_as_uint(d4.z), __float_as_uint(d4.w)};
        const unsigned pw = __shfl_up(cw[3], 1);    // prev lane, nodes {.,7}
        const unsigned nx = __shfl_down(cw[0], 1);  // next lane, nodes {0,.}
        unsigned* ap = Ab + kp8 * 65 + nq8 * 8;
        float cl = (nq8 > 0) ? bfhi(pw) : 0.f;      // left of node 0
#pragma unroll
        for (int j = 0; j < 4; j++) {
            const float ce = bflo(cw[j]), co = bfhi(cw[j]);   // nodes 2j, 2j+1
            const float ue = bflo(uw[j]), uo = bfhi(uw[j]);
            const float de = bflo(dw[j]), dd = bfhi(dw[j]);
            const float ro = (j < 3) ? bflo(cw[j + 1])
                                     : ((nq8 < 7) ? bflo(nx) : 0.f);
            ap[2 * j]     = pack_split((su * ue + sd * de + cl + co) * inv8[2 * j]);
            ap[2 * j + 1] = pack_split((su * uo + sd * dd + ce + ro) * inv8[2 * j + 1]);
            cl = co;                                 // left of next even
        }
    };
    auto consume = [&](const unsigned* Ab) {
#pragma unroll
        for (int nt = 0; nt < 4; nt++) {
            const unsigned* bp = Ab + (quad * 8) * 65 + nt * 16 + nl;
            bf16x8 bh, bl; frag_packed(bp, bh, bl);
            acc[nt][0] = MFMA(V[0][0], bh, acc[nt][0]);
            acc[nt][0] = MFMA(V[0][0], bl, acc[nt][0]);
            acc[nt][0] = MFMA(V[0][1], bh, acc[nt][0]);
            acc[nt][1] = MFMA(V[1][0], bh, acc[nt][1]);
            acc[nt][1] = MFMA(V[1][0], bl, acc[nt][1]);
            acc[nt][1] = MFMA(V[1][1], bh, acc[nt][1]);
        }
    };

    // prologue: two quarters in flight before the first stage wait
    wload(0);
    sload(0, 0);
    if (NQ > 1) sload(1, 1);
    stage(As[0], 0);           // waits set0 only; set1 stays in flight
    if (NQ > 2) sload(2, 0);   // refill set0 -> two quarters ahead
    block_sync_lgkm();

#pragma unroll
    for (int q = 0; q < NQ; q++) {
        consume(As[q & 1]);                        // no drain
        if (q + 1 < NQ) {
            wload(q + 1);
            stage(As[(q + 1) & 1], (q + 1) & 1);   // set loaded 2 phases ago
            if (q + 3 < NQ) sload(q + 3, (q + 3) & 1);
            block_sync_lgkm();                     // globals stay in flight
        }
    }

    // ---- epilogue: + rowsum*bias, relu ----
    if (!MEAN) {
#pragma unroll
        for (int ftl = 0; ftl < 2; ftl++) {
            const int fb = 32 * w + 16 * ftl + quad * 4;
            const float b0 = bias[fb], b1 = bias[fb + 1], b2 = bias[fb + 2], b3 = bias[fb + 3];
#pragma unroll
            for (int nt = 0; nt < 4; nt++) {
                const int n = 16 * nt + nl;
                const int deg = (row > 0) + (row < 63) + (n > 0) + (n < 63);
                const float rs = (float)deg / ((float)deg + 1e-6f);
                ushort* op = hout + ((size_t)(b * 128 + fb) << 12) + row * 64 + n;
                op[0]        = bf16h(fmaxf(acc[nt][ftl][0] + rs * b0, 0.f));
                op[1u << 12] = bf16h(fmaxf(acc[nt][ftl][1] + rs * b1, 0.f));
                op[2u << 12] = bf16h(fmaxf(acc[nt][ftl][2] + rs * b2, 0.f));
                op[3u << 12] = bf16h(fmaxf(acc[nt][ftl][3] + rs * b3, 0.f));
            }
        }
    } else {
#pragma unroll
        for (int ftl = 0; ftl < 2; ftl++) {
            const int fb = 32 * w + 16 * ftl + quad * 4;
#pragma unroll
            for (int reg = 0; reg < 4; reg++) {
                const float bv = bias[fb + reg];
                float v = 0.f;
#pragma unroll
                for (int nt = 0; nt < 4; nt++) {
                    const int n = 16 * nt + nl;
                    const int deg = (row > 0) + (row < 63) + (n > 0) + (n < 63);
                    const float rs = (float)deg / ((float)deg + 1e-6f);
                    v += fmaxf(acc[nt][ftl][reg] + rs * bv, 0.f);
                }
                v += __shfl_xor(v, 1); v += __shfl_xor(v, 2);
                v += __shfl_xor(v, 4); v += __shfl_xor(v, 8);
                if (nl == 0) atomicAdd(&gsum[b * 128 + fb + reg], v * (1.f / 4096.f));
            }
        }
    }
}

// ---- readout: per-batch block, 2-layer MLP (fp32 vector) ----
__global__ __launch_bounds__(256) void readout_kernel(
    const float* __restrict__ gsum, const float* __restrict__ r1w,
    const float* __restrict__ r1b, const float* __restrict__ r2w,
    const float* __restrict__ r2b, float* __restrict__ out)
{
    __shared__ float gs[128];
    __shared__ float g2[256];
    const int b = blockIdx.x, tid = threadIdx.x;
    if (tid < 128) gs[tid] = gsum[b * 128 + tid];
    __syncthreads();
    float a = r1b[tid];
#pragma unroll 16
    for (int k = 0; k < 128; k++) a = fmaf(gs[k], r1w[k * 256 + tid], a);
    g2[tid] = fmaxf(a, 0.f);
    __syncthreads();
    float a2 = r2b[tid];
#pragma unroll 16
    for (int k = 0; k < 256; k++) a2 = fmaf(g2[k], r2w[k * 256 + tid], a2);
    out[b * 256 + tid] = fmaxf(a2, 0.f);
}

extern "C" void kernel_launch(void* const* d_in, const int* in_sizes, int n_in,
                              void* d_out, int out_size, void* d_ws, size_t ws_size,
                              hipStream_t stream)
{
    const float* obs = (const float*)d_in[0];
    const float* e1w = (const float*)d_in[1];
    const float* e1b = (const float*)d_in[2];
    const float* e2w = (const float*)d_in[3];
    const float* e2b = (const float*)d_in[4];
    const float* g1w = (const float*)d_in[5];
    const float* g1b = (const float*)d_in[6];
    const float* g2w = (const float*)d_in[7];
    const float* g2b = (const float*)d_in[8];
    const float* g3w = (const float*)d_in[9];
    const float* g3b = (const float*)d_in[10];
    const float* r1w = (const float*)d_in[11];
    const float* r1b = (const float*)d_in[12];
    const float* r2w = (const float*)d_in[13];
    const float* r2b = (const float*)d_in[14];
    float* out = (float*)d_out;

    ushort* h0 = (ushort*)d_ws;                                   // 8 MB
    ushort* h1 = (ushort*)((char*)d_ws + (16u << 20));            // 16 MB
    ushort* h2 = (ushort*)((char*)d_ws + (48u << 20));            // 16 MB
    float* gsum = (float*)((char*)d_ws + (80u << 20));            // 8 KB
    ushort* wfb = (ushort*)((char*)d_ws + (80u << 20) + 8192u);   // 184 KB

    hipLaunchKernelGGL(prep_embed_kernel, dim3(1024), dim3(256), 0, stream,
                       obs, e1w, e1b, e2w, e2b, g1w, g2w, g3w, wfb, gsum, h0);
    hipLaunchKernelGGL((gnn_kernel<64, false>), dim3(1024), dim3(256), 0, stream,
                       h0, wfb + 12288, g1b, h1, nullptr);
    hipLaunchKernelGGL((gnn_kernel<128, false>), dim3(1024), dim3(256), 0, stream,
                       h1, wfb + 28672, g2b, h2, nullptr);
    hipLaunchKernelGGL((gnn_kernel<128, true>), dim3(1024), dim3(256), 0, stream,
                       h2, wfb + 61440, g3b, nullptr, gsum);
    hipLaunchKernelGGL(readout_kernel, dim3(16), dim3(256), 0, stream,
                       gsum, r1w, r1b, r2w, r2b, out);
}

// Round 5
// 148.709 us; speedup vs baseline: 1.2347x; 1.0076x over previous
//
#include <hip/hip_runtime.h>

// R22 = R21 with FULL-DEPTH staging in gnn: all NQ quarters' h-loads issued
// in the prologue (bf16 made a quarter = 3 float4 = 12 VGPR, so K=128's 4
// quarters fit in S[12] = 48 VGPR; total ~115 VGPR < 128 @ 4 waves/SIMD).
// Steady-state loop issues NO h loads; stage(q) waits on loads issued
// q compute-phases + prologue earlier -> exposed HBM latency ~once per
// LAYER instead of once per quarter. R21 (2-deep, bf16) validated the
// latency-exposure theory: 159.6 -> 149.8us, absmax 4.9e-4 as predicted.
// History: R18 gnn-fusion regressed (L2 self-eviction); R16 fused readout
// regressed (device-scope sync storm); R12 feat-split regressed (read dup);
// R20 prep restructure neutral (kept). Intermediates bf16 feature-major.
//
// GNN layer exact rewrite: h' = relu( agg(h) @ W + rowsum*b ).
// fp32 aggregate a = hi + lo (bf16); 3 MFMAs: hi*wh + hi*wl + lo*wh.
//
// MFMA 16x16x32 bf16 layouts (verified m89/m120):
//   A (MxK): m = lane&15, k = quad*8 + j    B (KxN): n = lane&15, k = quad*8 + j
//   C/D: col(N) = lane&15, row(M) = quad*4 + reg

typedef __attribute__((ext_vector_type(8))) short bf16x8;
typedef __attribute__((ext_vector_type(4))) float f32x4;
#define MFMA(a, b, c) __builtin_amdgcn_mfma_f32_16x16x32_bf16(a, b, c, 0, 0, 0)

// barrier with LDS visibility but WITHOUT draining global loads:
// s_waitcnt imm 0xC07F = vmcnt(63) expcnt(7) lgkmcnt(0)
__device__ inline void block_sync_lgkm() {
    asm volatile("" ::: "memory");
    __builtin_amdgcn_s_waitcnt(0xC07F);
    __builtin_amdgcn_s_barrier();
    asm volatile("" ::: "memory");
}

__device__ inline ushort bf16h(float x) {
    unsigned u = __float_as_uint(x);
    return (ushort)((u + 0x7fffu + ((u >> 16) & 1u)) >> 16);
}
__device__ inline void split_bf16(float x, ushort& hi, ushort& lo) {
    hi = bf16h(x);
    lo = bf16h(x - __uint_as_float(((unsigned)hi) << 16));
}
// packed (hi16 << 16) | lo16 ; hi = RNE, lo = truncation
__device__ inline unsigned pack_split(float x) {
    unsigned u = __float_as_uint(x);
    unsigned hi = (u + 0x7fffu + ((u >> 16) & 1u)) >> 16;
    float r = x - __uint_as_float(hi << 16);
    return (hi << 16) | (__float_as_uint(r) >> 16);
}
// bf16 pair in a u32: even node = low ushort, odd node = high ushort
__device__ inline float bflo(unsigned w) { return __uint_as_float(w << 16); }
__device__ inline float bfhi(unsigned w) { return __uint_as_float(w & 0xFFFF0000u); }
// 8 packed u32 (stride 65) -> hi/lo bf16x8 fragments
__device__ inline void frag_packed(const unsigned* bp, bf16x8& bh, bf16x8& bl) {
    unsigned p[8];
#pragma unroll
    for (int j = 0; j < 8; j++) p[j] = bp[j * 65];
    union { bf16x8 v; unsigned d[4]; } H, L;
#pragma unroll
    for (int j = 0; j < 4; j++) {
        const unsigned e = p[2 * j], o = p[2 * j + 1];
        H.d[j] = (o & 0xFFFF0000u) | (e >> 16);
        L.d[j] = (o << 16) | (e & 0xFFFFu);
    }
    bh = H.v; bl = L.v;
}

// ---- launch 1: embed (1024 blocks); aux work folded into first 28 blocks ----
// g-frag unit (kc,t) = 2 planes x 512 ushorts; per layer unit idx = kc*8 + t.
// wfb ushort offsets: g1@12288 (16 units), g2@28672 (32), g3@61440 (32).
__global__ __launch_bounds__(256, 4) void prep_embed_kernel(
    const float* __restrict__ obs,
    const float* __restrict__ e1w, const float* __restrict__ e1b,
    const float* __restrict__ e2w, const float* __restrict__ e2b,
    const float* __restrict__ g1w, const float* __restrict__ g2w,
    const float* __restrict__ g3w, ushort* __restrict__ wf,
    float* __restrict__ gsum, ushort* __restrict__ h0)
{
    const int blk = blockIdx.x, tid = threadIdx.x;

    // ---- aux: g-weight prep (blk<20, 4 units/block) + gsum zero (blk<28).
    // Outputs consumed only by LATER launches -> no intra-kernel ordering.
    if (blk < 20) {
        const int u = blk * 4 + (tid >> 6);
        const int l = tid & 63;
        const float* src; int K, kc, t; ushort* dst;
        if (u < 16)      { src = g1w; K = 64;  kc = u >> 3;        t = u & 7; dst = wf + 12288; }
        else if (u < 48) { src = g2w; K = 128; kc = (u - 16) >> 3; t = (u - 16) & 7; dst = wf + 28672; }
        else             { src = g3w; K = 128; kc = (u - 48) >> 3; t = (u - 48) & 7; dst = wf + 61440; }
        ushort* uh = dst + ((kc * 8 + t) * 2 + 0) * 512 + l * 8;
        ushort* ul = dst + ((kc * 8 + t) * 2 + 1) * 512 + l * 8;
        const int fw = t * 16 + (l & 15);
        const int kb = kc * 32 + ((l >> 4) << 3);
#pragma unroll
        for (int j = 0; j < 8; j++) {
            const int k = kb + j;
            const float wv = (k < K) ? src[k * 128 + fw] : 0.f;
            ushort hi, lo; split_bf16(wv, hi, lo);
            uh[j] = hi; ul[j] = lo;
        }
    } else if (blk < 28) {
        gsum[(blk - 20) * 256 + tid] = 0.f;
    }

    // ---- embed: block = (b, row) = 64 nodes, fused 2-layer MLP via MFMA ----
    __shared__ unsigned lds[6240];         // Xs = lds[0..2080), Hs = lds+2080 (4160)
    // XCD remap ALIGNED with gnn readers: h0 rows land on the XCD that reads them
    const int ebid = ((blk & 7) << 7) | (blk >> 3);
    const int b = ebid >> 6, row = ebid & 63;
    const int lane = tid & 63, w = tid >> 6, quad = lane >> 4, nl = lane & 15;
    const int cp = tid >> 4, nq = tid & 15;

    // obs load issued early (used in phase X)
    const float4 x4 = *(const float4*)(obs + ((size_t)(b * 16 + cp) << 12) + row * 64 + nq * 4);

    // weight fragments DIRECT from global (e1w 4KB + e2w 16KB, L1-resident
    // after the first block on each CU; 64B-per-quad coalesced segments)
    float e1f[8], e2f[16];
    {
        const int f = 16 * w + nl;
#pragma unroll
        for (int j = 0; j < 8; j++) {
            const int k = quad * 8 + j;
            e1f[j] = (k < 16) ? e1w[k * 64 + f] : 0.f;
        }
#pragma unroll
        for (int kc = 0; kc < 2; kc++)
#pragma unroll
            for (int j = 0; j < 8; j++)
                e2f[kc * 8 + j] = e2w[(kc * 32 + quad * 8 + j) * 64 + f];
    }

    // phase X: stage obs packed (B-operand planes, k>=16 zeroed)
    unsigned* Xs = lds;
    unsigned* Hs = lds + 2080;
    {
        unsigned* xp = Xs + cp * 65 + nq * 4;
        xp[0] = pack_split(x4.x); xp[1] = pack_split(x4.y);
        xp[2] = pack_split(x4.z); xp[3] = pack_split(x4.w);
        unsigned* zp = Xs + (16 + cp) * 65 + nq * 4;
        zp[0] = 0u; zp[1] = 0u; zp[2] = 0u; zp[3] = 0u;
    }

    // build this wave's weight fragments in registers (A-operand, M=feats);
    // VALU-only, overlaps the weight-load latency before the barrier
    bf16x8 e1h, e1l, e2h[2], e2l[2];
#pragma unroll
    for (int j = 0; j < 8; j++) {
        ushort hi, lo; split_bf16(e1f[j], hi, lo);
        e1h[j] = (short)hi; e1l[j] = (short)lo;
    }
#pragma unroll
    for (int kc = 0; kc < 2; kc++)
#pragma unroll
        for (int j = 0; j < 8; j++) {
            ushort hi, lo; split_bf16(e2f[kc * 8 + j], hi, lo);
            e2h[kc][j] = (short)hi; e2l[kc][j] = (short)lo;
        }
    __syncthreads();

    // layer 1: wave w -> mid-feats 16w..16w+15
#pragma unroll
    for (int nt = 0; nt < 4; nt++) {
        const unsigned* bp = Xs + (quad * 8) * 65 + nt * 16 + nl;
        bf16x8 bh, bl; frag_packed(bp, bh, bl);
        f32x4 c = {0.f, 0.f, 0.f, 0.f};
        c = MFMA(e1h, bh, c); c = MFMA(e1h, bl, c); c = MFMA(e1l, bh, c);
#pragma unroll
        for (int reg = 0; reg < 4; reg++) {
            const int fm = 16 * w + quad * 4 + reg;
            Hs[fm * 65 + nt * 16 + nl] = pack_split(fmaxf(c[reg] + e1b[fm], 0.f));
        }
    }
    __syncthreads();

    // layer 2: K=64 (2 kc)
    f32x4 a2[4];
#pragma unroll
    for (int nt = 0; nt < 4; nt++) a2[nt] = (f32x4){0.f, 0.f, 0.f, 0.f};
#pragma unroll
    for (int kc = 0; kc < 2; kc++) {
#pragma unroll
        for (int nt = 0; nt < 4; nt++) {
            const unsigned* bp = Hs + (kc * 32 + quad * 8) * 65 + nt * 16 + nl;
            bf16x8 bh, bl; frag_packed(bp, bh, bl);
            a2[nt] = MFMA(e2h[kc], bh, a2[nt]);
            a2[nt] = MFMA(e2h[kc], bl, a2[nt]);
            a2[nt] = MFMA(e2l[kc], bh, a2[nt]);
        }
    }
#pragma unroll
    for (int reg = 0; reg < 4; reg++) {
        const int f = 16 * w + quad * 4 + reg;
        const float bv = e2b[f];
#pragma unroll
        for (int nt = 0; nt < 4; nt++)
            h0[((size_t)(b * 64 + f) << 12) + row * 64 + nt * 16 + nl] =
                bf16h(fmaxf(a2[nt][reg] + bv, 0.f));
    }
}

// ---- GNN layer: bf16 input, FULL-depth staging (all quarters in flight) ----
template <int K, bool MEAN>
__global__ __launch_bounds__(256, 4) void gnn_kernel(
    const ushort* __restrict__ hin, const ushort* __restrict__ wf,
    const float* __restrict__ bias, ushort* __restrict__ hout,
    float* __restrict__ gsum)
{
    constexpr int NQ = K / 32;            // quarters of 32 planes (= one kc each)
    __shared__ unsigned As[2][32 * 65];   // packed hi|lo, dbuf
    const int tid = threadIdx.x;
    // XCD-contiguous remap: consecutive rows on the same XCD (R7: FETCH 49->18MB)
    const int bid = ((blockIdx.x & 7) << 7) | (blockIdx.x >> 3);
    const int b = bid >> 6, row = bid & 63;
    const int lane = tid & 63, w = tid >> 6, quad = lane >> 4, nl = lane & 15;
    const int kp8 = tid >> 3, nq8 = tid & 7;   // plane 0-31, 8-node group
    const ushort* hb = hin + (size_t)b * K * 4096;
    const int rowu = (row > 0) ? row - 1 : row;
    const int rowd = (row < 63) ? row + 1 : row;
    const float su = (row > 0) ? 1.f : 0.f;
    const float sd = (row < 63) ? 1.f : 0.f;
    float inv8[8];
#pragma unroll
    for (int i = 0; i < 8; i++) {
        const int n = nq8 * 8 + i;
        const int deg = (row > 0) + (row < 63) + (n > 0) + (n < 63);
        inv8[i] = 1.f / ((float)deg + 1e-6f);
    }

    const ushort* wfl = wf + lane * 8;
    f32x4 acc[4][2];
#pragma unroll
    for (int nt = 0; nt < 4; nt++) {
        acc[nt][0] = (f32x4){0.f, 0.f, 0.f, 0.f};
        acc[nt][1] = (f32x4){0.f, 0.f, 0.f, 0.f};
    }

    float4 S[3 * NQ];     // FULL depth: every quarter staged (12 VGPR each)
    bf16x8 V[2][2];       // current quarter's weights [ftl][hi/lo]

    auto sload = [&](int q) {             // one quarter = 32 planes, 3 loads
        const int kg = q * 32 + kp8;
        const ushort* pk = hb + ((size_t)kg << 12) + nq8 * 8;
        S[q * 3 + 0] = *(const float4*)(pk + row * 64);
        S[q * 3 + 1] = *(const float4*)(pk + rowu * 64);
        S[q * 3 + 2] = *(const float4*)(pk + rowd * 64);
    };
    auto wload = [&](int q) {
#pragma unroll
        for (int ftl = 0; ftl < 2; ftl++) {
            V[ftl][0] = *(const bf16x8*)(wfl + ((q * 8 + 2 * w + ftl) * 2) * 512);
            V[ftl][1] = *(const bf16x8*)(wfl + ((q * 8 + 2 * w + ftl) * 2 + 1) * 512);
        }
    };
    auto stage = [&](unsigned* Ab, int q) {
        const float4 c4 = S[q * 3 + 0];
        const float4 u4 = S[q * 3 + 1];
        const float4 d4 = S[q * 3 + 2];
        const unsigned cw[4] = {__float_as_uint(c4.x), __float_as_uint(c4.y),
                                __float_as_uint(c4.z), __float_as_uint(c4.w)};
        const unsigned uw[4] = {__float_as_uint(u4.x), __float_as_uint(u4.y),
                                __float_as_uint(u4.z), __float_as_uint(u4.w)};
        const unsigned dw[4] = {__float_as_uint(d4.x), __float_as_uint(d4.y),
                                __float_as_uint(d4.z), __float_as_uint(d4.w)};
        const unsigned pw = __shfl_up(cw[3], 1);    // prev lane, nodes {.,7}
        const unsigned nx = __shfl_down(cw[0], 1);  // next lane, nodes {0,.}
        unsigned* ap = Ab + kp8 * 65 + nq8 * 8;
        float cl = (nq8 > 0) ? bfhi(pw) : 0.f;      // left of node 0
#pragma unroll
        for (int j = 0; j < 4; j++) {
            const float ce = bflo(cw[j]), co = bfhi(cw[j]);   // nodes 2j, 2j+1
            const float ue = bflo(uw[j]), uo = bfhi(uw[j]);
            const float de = bflo(dw[j]), dd = bfhi(dw[j]);
            const float ro = (j < 3) ? bflo(cw[j + 1])
                                     : ((nq8 < 7) ? bflo(nx) : 0.f);
            ap[2 * j]     = pack_split((su * ue + sd * de + cl + co) * inv8[2 * j]);
            ap[2 * j + 1] = pack_split((su * uo + sd * dd + ce + ro) * inv8[2 * j + 1]);
            cl = co;                                 // left of next even
        }
    };
    auto consume = [&](const unsigned* Ab) {
#pragma unroll
        for (int nt = 0; nt < 4; nt++) {
            const unsigned* bp = Ab + (quad * 8) * 65 + nt * 16 + nl;
            bf16x8 bh, bl; frag_packed(bp, bh, bl);
            acc[nt][0] = MFMA(V[0][0], bh, acc[nt][0]);
            acc[nt][0] = MFMA(V[0][0], bl, acc[nt][0]);
            acc[nt][0] = MFMA(V[0][1], bh, acc[nt][0]);
            acc[nt][1] = MFMA(V[1][0], bh, acc[nt][1]);
            acc[nt][1] = MFMA(V[1][0], bl, acc[nt][1]);
            acc[nt][1] = MFMA(V[1][1], bh, acc[nt][1]);
        }
    };

    // prologue: issue ALL h loads for the layer; only then wait on set 0
    wload(0);
#pragma unroll
    for (int qq = 0; qq < NQ; qq++) sload(qq);
    stage(As[0], 0);           // waits set0; sets 1..NQ-1 stay in flight
    block_sync_lgkm();

#pragma unroll
    for (int q = 0; q < NQ; q++) {
        consume(As[q & 1]);                        // no drain
        if (q + 1 < NQ) {
            wload(q + 1);
            stage(As[(q + 1) & 1], q + 1);         // loads issued in prologue
            block_sync_lgkm();                     // globals stay in flight
        }
    }

    // ---- epilogue: + rowsum*bias, relu ----
    if (!MEAN) {
#pragma unroll
        for (int ftl = 0; ftl < 2; ftl++) {
            const int fb = 32 * w + 16 * ftl + quad * 4;
            const float b0 = bias[fb], b1 = bias[fb + 1], b2 = bias[fb + 2], b3 = bias[fb + 3];
#pragma unroll
            for (int nt = 0; nt < 4; nt++) {
                const int n = 16 * nt + nl;
                const int deg = (row > 0) + (row < 63) + (n > 0) + (n < 63);
                const float rs = (float)deg / ((float)deg + 1e-6f);
                ushort* op = hout + ((size_t)(b * 128 + fb) << 12) + row * 64 + n;
                op[0]        = bf16h(fmaxf(acc[nt][ftl][0] + rs * b0, 0.f));
                op[1u << 12] = bf16h(fmaxf(acc[nt][ftl][1] + rs * b1, 0.f));
                op[2u << 12] = bf16h(fmaxf(acc[nt][ftl][2] + rs * b2, 0.f));
                op[3u << 12] = bf16h(fmaxf(acc[nt][ftl][3] + rs * b3, 0.f));
            }
        }
    } else {
#pragma unroll
        for (int ftl = 0; ftl < 2; ftl++) {
            const int fb = 32 * w + 16 * ftl + quad * 4;
#pragma unroll
            for (int reg = 0; reg < 4; reg++) {
                const float bv = bias[fb + reg];
                float v = 0.f;
#pragma unroll
                for (int nt = 0; nt < 4; nt++) {
                    const int n = 16 * nt + nl;
                    const int deg = (row > 0) + (row < 63) + (n > 0) + (n < 63);
                    const float rs = (float)deg / ((float)deg + 1e-6f);
                    v += fmaxf(acc[nt][ftl][reg] + rs * bv, 0.f);
                }
                v += __shfl_xor(v, 1); v += __shfl_xor(v, 2);
                v += __shfl_xor(v, 4); v += __shfl_xor(v, 8);
                if (nl == 0) atomicAdd(&gsum[b * 128 + fb + reg], v * (1.f / 4096.f));
            }
        }
    }
}

// ---- readout: per-batch block, 2-layer MLP (fp32 vector) ----
__global__ __launch_bounds__(256) void readout_kernel(
    const float* __restrict__ gsum, const float* __restrict__ r1w,
    const float* __restrict__ r1b, const float* __restrict__ r2w,
    const float* __restrict__ r2b, float* __restrict__ out)
{
    __shared__ float gs[128];
    __shared__ float g2[256];
    const int b = blockIdx.x, tid = threadIdx.x;
    if (tid < 128) gs[tid] = gsum[b * 128 + tid];
    __syncthreads();
    float a = r1b[tid];
#pragma unroll 16
    for (int k = 0; k < 128; k++) a = fmaf(gs[k], r1w[k * 256 + tid], a);
    g2[tid] = fmaxf(a, 0.f);
    __syncthreads();
    float a2 = r2b[tid];
#pragma unroll 16
    for (int k = 0; k < 256; k++) a2 = fmaf(g2[k], r2w[k * 256 + tid], a2);
    out[b * 256 + tid] = fmaxf(a2, 0.f);
}

extern "C" void kernel_launch(void* const* d_in, const int* in_sizes, int n_in,
                              void* d_out, int out_size, void* d_ws, size_t ws_size,
                              hipStream_t stream)
{
    const float* obs = (const float*)d_in[0];
    const float* e1w = (const float*)d_in[1];
    const float* e1b = (const float*)d_in[2];
    const float* e2w = (const float*)d_in[3];
    const float* e2b = (const float*)d_in[4];
    const float* g1w = (const float*)d_in[5];
    const float* g1b = (const float*)d_in[6];
    const float* g2w = (const float*)d_in[7];
    const float* g2b = (const float*)d_in[8];
    const float* g3w = (const float*)d_in[9];
    const float* g3b = (const float*)d_in[10];
    const float* r1w = (const float*)d_in[11];
    const float* r1b = (const float*)d_in[12];
    const float* r2w = (const float*)d_in[13];
    const float* r2b = (const float*)d_in[14];
    float* out = (float*)d_out;

    ushort* h0 = (ushort*)d_ws;                                   // 8 MB
    ushort* h1 = (ushort*)((char*)d_ws + (16u << 20));            // 16 MB
    ushort* h2 = (ushort*)((char*)d_ws + (48u << 20));            // 16 MB
    float* gsum = (float*)((char*)d_ws + (80u << 20));            // 8 KB
    ushort* wfb = (ushort*)((char*)d_ws + (80u << 20) + 8192u);   // 184 KB

    hipLaunchKernelGGL(prep_embed_kernel, dim3(1024), dim3(256), 0, stream,
                       obs, e1w, e1b, e2w, e2b, g1w, g2w, g3w, wfb, gsum, h0);
    hipLaunchKernelGGL((gnn_kernel<64, false>), dim3(1024), dim3(256), 0, stream,
                       h0, wfb + 12288, g1b, h1, nullptr);
    hipLaunchKernelGGL((gnn_kernel<128, false>), dim3(1024), dim3(256), 0, stream,
                       h1, wfb + 28672, g2b, h2, nullptr);
    hipLaunchKernelGGL((gnn_kernel<128, true>), dim3(1024), dim3(256), 0, stream,
                       h2, wfb + 61440, g3b, nullptr, gsum);
    hipLaunchKernelGGL(readout_kernel, dim3(16), dim3(256), 0, stream,
                       gsum, r1w, r1b, r2w, r2b, out);
}